// Round 7
// baseline (1545.779 us; speedup 1.0000x reference)
//
#include <hip/hip_runtime.h>
#include <hip/hip_fp16.h>

#define NB 8
#define P 1024
#define D 64
#define EPSF 0.1f
#define INV_EPS 10.0f
#define MAX_IT 100
#define EPS_LOG_MU (-0.693146162f)     // eps*log(1/P + 1e-8)
#define EPSF_LN2   (0.0693147181f)     // eps*ln2
#define SCALEW     (14.4269504089f)    // INV_EPS * log2(e)
#define ZSC        (-14.4269504089f)   // -INV_EPS * log2(e)  (gemm output scale)
#define IB 512                          // iter_k blocks
#define TPB_I 512                       // threads per iter block (8 waves)
#define BPB 128                         // blocks per batch (pair-split)

// ws layout in FLOATS (identical to R4/R5 -- proven available)
#define HALF_F (NB * P * P / 2)
#define OFF_Z    0                           // z  = -C/eps*log2e, row-major fp16
#define OFF_ZT   (HALF_F)
#define OFF_U    (2 * HALF_F)
#define OFF_V    (OFF_U + NB * P)
#define OFF_X2   (OFF_V + NB * P)
#define OFF_Y2   (OFF_X2 + NB * P)
#define OFF_UH   (OFF_Y2 + NB * P)           // u history: MAX_IT * NB*P
#define OFF_DU   (OFF_UH + MAX_IT * NB * P)  // du partials: MAX_IT * IB
#define OFF_BAR  (OFF_DU + MAX_IT * IB)      // 256 uints (8 padded counters)
#define OFF_T    (OFF_BAR + 256)
#define OFF_COST (OFF_T + 64)
#define WS_FLOATS (OFF_COST + 64)

__device__ __forceinline__ void publish_f(float* p, float v) {
    __hip_atomic_store(p, v, __ATOMIC_RELAXED, __HIP_MEMORY_SCOPE_SYSTEM);
}

// ---------------- init ----------------
__global__ __launch_bounds__(256)
void init_k(const float* __restrict__ x, const float* __restrict__ y,
            float* __restrict__ ws)
{
    const int g = blockIdx.x * 256 + threadIdx.x;
    if (g < NB * P) {
        const float4* xr = (const float4*)(x + (size_t)g * D);
        const float4* yr = (const float4*)(y + (size_t)g * D);
        float sx = 0.f, sy = 0.f;
#pragma unroll
        for (int k = 0; k < D / 4; k++) {
            float4 a = xr[k], b = yr[k];
            sx = fmaf(a.x, a.x, fmaf(a.y, a.y, fmaf(a.z, a.z, fmaf(a.w, a.w, sx))));
            sy = fmaf(b.x, b.x, fmaf(b.y, b.y, fmaf(b.z, b.z, fmaf(b.w, b.w, sy))));
        }
        ws[OFF_X2 + g] = sx; ws[OFF_Y2 + g] = sy;
    }
    if (g < 256) ((unsigned*)(ws + OFF_BAR))[g] = 0u;
    if (g < 64)  ws[OFF_COST + g] = 0.f;
}

// ---------------- z and z^T via LDS GEMM, fp16 (log2-domain) ----------------
__global__ __launch_bounds__(256)
void gemm_k(const float* __restrict__ x, const float* __restrict__ y,
            float* __restrict__ ws)
{
    float* x2 = ws + OFF_X2;
    float* y2 = ws + OFF_Y2;
    const int tid   = threadIdx.x;
    const int half_ = blockIdx.x >> 9;
    const int bid   = blockIdx.x & 511;
    const int nB    = bid & 7;
    const int inner = bid >> 3;

    const float* A  = half_ ? y : x;
    const float* B  = half_ ? x : y;
    const float* ra = (half_ ? y2 : x2) + nB * P;
    const float* rb = (half_ ? x2 : y2) + nB * P;
    __half* out = (__half*)(ws + (half_ ? OFF_ZT : OFF_Z)) + (size_t)nB * P * P;

    __shared__ float xs [64 * 68];
    __shared__ float ysT[64 * 64];

    for (int k4 = 0; k4 < 4; k4++) {
        const int t  = inner * 4 + k4;
        const int ti = t >> 4, tj = t & 15;
        const float* abase = A + (size_t)(nB * P + ti * 64) * D;
        const float* bbase = B + (size_t)(nB * P + tj * 64) * D;
#pragma unroll
        for (int k = 0; k < 4; k++) {
            const int f = k * 1024 + tid * 4;
            const int r = f >> 6, c = f & 63;
            float4 a = *(const float4*)(abase + f);
            *(float4*)(xs + r * 68 + c) = a;
            float4 b = *(const float4*)(bbase + f);
            const int pr  = r >> 2;
            const int r3  = r & 3;
            const int t15 = c >> 2;
            ysT[(c + 0) * 64 + (((pr ^ t15) & 15) << 2) + r3] = b.x;
            ysT[(c + 1) * 64 + (((pr ^ t15) & 15) << 2) + r3] = b.y;
            ysT[(c + 2) * 64 + (((pr ^ t15) & 15) << 2) + r3] = b.z;
            ysT[(c + 3) * 64 + (((pr ^ t15) & 15) << 2) + r3] = b.w;
        }
        __syncthreads();
        const int r0 = tid >> 4;
        const int g  = tid & 15;
        const int c0 = g << 2;
#pragma unroll
        for (int rr = 0; rr < 4; rr++) {
            const int row = rr * 16 + r0;
            const float* xrow = xs + row * 68;
            float s0 = 0.f, s1 = 0.f, s2 = 0.f, s3 = 0.f;
#pragma unroll
            for (int d = 0; d < 64; d++) {
                const float xv = xrow[d];
                const float4 yv = *(const float4*)(ysT + d * 64 + ((g ^ ((d >> 2) & 15)) << 2));
                s0 = fmaf(xv, yv.x, s0); s1 = fmaf(xv, yv.y, s1);
                s2 = fmaf(xv, yv.z, s2); s3 = fmaf(xv, yv.w, s3);
            }
            const int gr = ti * 64 + row;
            const int gc = tj * 64 + c0;
            const float xq = ra[gr];
            union { unsigned long long u64; __half h[4]; } p;
            p.h[0] = __float2half_rn(fmaxf(xq + rb[gc + 0] - 2.f * s0, 0.f) * ZSC);
            p.h[1] = __float2half_rn(fmaxf(xq + rb[gc + 1] - 2.f * s1, 0.f) * ZSC);
            p.h[2] = __float2half_rn(fmaxf(xq + rb[gc + 2] - 2.f * s2, 0.f) * ZSC);
            p.h[3] = __float2half_rn(fmaxf(xq + rb[gc + 3] - 2.f * s3, 0.f) * ZSC);
            *(unsigned long long*)(out + (size_t)gr * P + gc) = p.u64;
        }
        __syncthreads();
    }
}

#define MAX4(a,b,c,d) fmaxf(fmaxf(a,b),fmaxf(c,d))

// LSE over one register-resident row; weights (prescaled) from LDS.
// Column mapping: lane's cols = q*256 + lane*4 + e  (consistent on both sides).
__device__ __forceinline__ float lse16(const uint2* fz, const float* wst, int lane)
{
    float z[16];
#pragma unroll
    for (int q = 0; q < 4; q++) {
        const float4 w = *(const float4*)(wst + q * 256 + lane * 4);
        const float2 f01 = __half22float2(*(const __half2*)&fz[q].x);
        const float2 f23 = __half22float2(*(const __half2*)&fz[q].y);
        z[4 * q + 0] = f01.x + w.x;
        z[4 * q + 1] = f01.y + w.y;
        z[4 * q + 2] = f23.x + w.z;
        z[4 * q + 3] = f23.y + w.w;
    }
    float m = fmaxf(fmaxf(MAX4(z[0], z[1], z[2], z[3]), MAX4(z[4], z[5], z[6], z[7])),
                    fmaxf(MAX4(z[8], z[9], z[10], z[11]), MAX4(z[12], z[13], z[14], z[15])));
#pragma unroll
    for (int off = 32; off; off >>= 1) m = fmaxf(m, __shfl_xor(m, off, 64));
    float e[16];
#pragma unroll
    for (int q = 0; q < 16; q++) e[q] = exp2f(z[q] - m);
#pragma unroll
    for (int q = 0; q < 8; q++) e[q] += e[q + 8];
#pragma unroll
    for (int q = 0; q < 4; q++) e[q] += e[q + 4];
    float s = (e[0] + e[1]) + (e[2] + e[3]);
#pragma unroll
    for (int off = 32; off; off >>= 1) s += __shfl_xor(s, off, 64);
    return EPS_LOG_MU - EPSF_LN2 * (m + __log2f(s));
}

// stage 1024 weights into LDS, prescaled; system-scope 8B loads
__device__ __forceinline__ void stageW(float* wst, const float* src, int tid, bool zero)
{
    if (zero) {
        wst[tid * 2] = 0.f; wst[tid * 2 + 1] = 0.f;
    } else {
        float2 w;
        asm volatile("global_load_dwordx2 %0, %1, off sc0 sc1\n\ts_waitcnt vmcnt(0)"
                     : "=&v"(w) : "v"(src + tid * 2) : "memory");
        wst[tid * 2]     = w.x * SCALEW;
        wst[tid * 2 + 1] = w.y * SCALEW;
    }
}

__device__ __forceinline__ void arrive(unsigned* ctr) {
    __hip_atomic_fetch_add(ctr, 1u, __ATOMIC_RELAXED, __HIP_MEMORY_SCOPE_AGENT);
}
__device__ __forceinline__ void waitc(unsigned* ctr, unsigned target) {
    unsigned g = 0;
    while (__hip_atomic_load(ctr, __ATOMIC_RELAXED, __HIP_MEMORY_SCOPE_SYSTEM) < target) {
        __builtin_amdgcn_s_sleep(2);
        if (++g > (1u << 15)) break;     // degrade (visibly wrong), never hang
    }
}

// ---------------- persistent iteration kernel ----------------
// 512 blocks x 512 threads. Block owns batch pair (A,B): split-phase schedule
// rowA/rowB/colA/colB hides each barrier behind the other batch's compute.
// Each wave holds 1 z-row + 1 zT-row per batch in registers (4 rows x 8 VGPR).
__global__ __launch_bounds__(TPB_I, 4)
void iter_k(float* __restrict__ ws)
{
    const int tid  = threadIdx.x;
    const int wid  = tid >> 6;
    const int lane = tid & 63;
    const int pair = blockIdx.x & 3;        // 4 pairs of batches
    const int pidx = blockIdx.x >> 2;       // 0..127 within pair
    const int bA   = pair * 2, bB = pair * 2 + 1;
    const int rowIdx = pidx * 8 + wid;      // 0..1023

    float* uh  = ws + OFF_UH;
    float* v   = ws + OFF_V;
    float* dup = ws + OFF_DU;

    __shared__ float wstage[P];             // 4 KB staged weights
    __shared__ float duRed[16];

    // register-resident fragments, permuted column mapping q*256+lane*4
    uint2 fzA[4], ftA[4], fzB[4], ftB[4];
    {
        const __half* zA  = (const __half*)(ws + OFF_Z)  + (size_t)bA * P * P + (size_t)rowIdx * P;
        const __half* tA  = (const __half*)(ws + OFF_ZT) + (size_t)bA * P * P + (size_t)rowIdx * P;
        const __half* zB  = (const __half*)(ws + OFF_Z)  + (size_t)bB * P * P + (size_t)rowIdx * P;
        const __half* tB  = (const __half*)(ws + OFF_ZT) + (size_t)bB * P * P + (size_t)rowIdx * P;
#pragma unroll
        for (int q = 0; q < 4; q++) {
            const int o = q * 256 + lane * 4;
            fzA[q] = *(const uint2*)(zA + o);
            ftA[q] = *(const uint2*)(tA + o);
            fzB[q] = *(const uint2*)(zB + o);
            ftB[q] = *(const uint2*)(tB + o);
        }
    }

    unsigned* ctrA = (unsigned*)(ws + OFF_BAR) + bA * 32;
    unsigned* ctrB = (unsigned*)(ws + OFF_BAR) + bB * 32;
    float* vbA = v + bA * P;
    float* vbB = v + bB * P;

    float uoldA = 0.f, uoldB = 0.f;

    for (int t = 0; t < MAX_IT; t++) {
        float* uhT = uh + (size_t)t * (NB * P);
        const unsigned base = 256u * t;

        // ---- row A (precondition ctrA >= base, satisfied on entry)
        stageW(wstage, vbA, tid, t == 0);
        __syncthreads();
        {
            const float un = lse16(fzA, wstage, lane);
            if (lane == 0) { publish_f(&uhT[bA * P + rowIdx], un); duRed[wid] = fabsf(un - uoldA); }
            uoldA = un;
        }
        __syncthreads();
        if (tid == 0) {
            arrive(ctrA);
            asm volatile("" ::: "memory");
            waitc(ctrB, base);               // rowB needs v_{t-1}^B
        }
        __syncthreads();

        // ---- row B
        stageW(wstage, vbB, tid, t == 0);
        __syncthreads();
        {
            const float un = lse16(fzB, wstage, lane);
            if (lane == 0) { publish_f(&uhT[bB * P + rowIdx], un); duRed[8 + wid] = fabsf(un - uoldB); }
            uoldB = un;
        }
        __syncthreads();
        if (tid == 0) {
            float d = 0.f;
#pragma unroll
            for (int k = 0; k < 16; k++) d += duRed[k];
            dup[t * IB + blockIdx.x] = d;
            arrive(ctrB);
            asm volatile("" ::: "memory");
            waitc(ctrA, base + 128);         // colA needs u_t^A
        }
        __syncthreads();

        // ---- col A
        stageW(wstage, uhT + bA * P, tid, false);
        __syncthreads();
        {
            const float vn = lse16(ftA, wstage, lane);
            if (lane == 0) publish_f(&vbA[rowIdx], vn);
        }
        __syncthreads();
        if (tid == 0) {
            arrive(ctrA);
            asm volatile("" ::: "memory");
            waitc(ctrB, base + 128);         // colB needs u_t^B
        }
        __syncthreads();

        // ---- col B
        stageW(wstage, uhT + bB * P, tid, false);
        __syncthreads();
        {
            const float vn = lse16(ftB, wstage, lane);
            if (lane == 0) publish_f(&vbB[rowIdx], vn);
        }
        __syncthreads();
        if (tid == 0) {
            arrive(ctrB);
            asm volatile("" ::: "memory");
            waitc(ctrA, base + 256);         // next rowA needs v_t^A
        }
        __syncthreads();
    }
}

// ---------------- find T, restore u_T ----------------
__global__ __launch_bounds__(1024)
void findT_k(float* __restrict__ ws)
{
    __shared__ float Spart[1024];
    __shared__ float S[MAX_IT];
    __shared__ int Ts;
    const int tid = threadIdx.x;

    {
        const int t = tid >> 3, sub = tid & 7;
        float s = 0.f;
        if (t < MAX_IT) {
            const float* dp = ws + OFF_DU + t * IB + sub * 64;
            for (int i = 0; i < 64; i++) s += dp[i];
        }
        Spart[tid] = s;
    }
    __syncthreads();
    if (tid < MAX_IT) {
        float s = 0.f;
#pragma unroll
        for (int k = 0; k < 8; k++) s += Spart[tid * 8 + k];
        S[tid] = s;
    }
    __syncthreads();
    if (tid == 0) {
        int T = MAX_IT - 1;
        for (int t = 0; t < MAX_IT; t++) if (S[t] < 0.8f) { T = t; break; }
        Ts = T;
        *(int*)(ws + OFF_T) = T;
    }
    __syncthreads();
    const int T = Ts;
    const float* src = ws + OFF_UH + (size_t)T * (NB * P);
    float* u = ws + OFF_U;
    for (int i = tid; i < NB * P; i += 1024) u[i] = src[i];
    if (tid < 64) ws[OFF_COST + tid] = 0.f;
}

// args: z' (log2-domain fp16) + w*SCALEW -> 8 args
__device__ __forceinline__ void args8(uint4 c, float4 w0, float4 w1, float* zp)
{
    const __half2* h = (const __half2*)&c;
    float2 f;
    f = __half22float2(h[0]); zp[0] = fmaf(w0.x, SCALEW, f.x); zp[1] = fmaf(w0.y, SCALEW, f.y);
    f = __half22float2(h[1]); zp[2] = fmaf(w0.z, SCALEW, f.x); zp[3] = fmaf(w0.w, SCALEW, f.y);
    f = __half22float2(h[2]); zp[4] = fmaf(w1.x, SCALEW, f.x); zp[5] = fmaf(w1.y, SCALEW, f.y);
    f = __half22float2(h[3]); zp[6] = fmaf(w1.z, SCALEW, f.x); zp[7] = fmaf(w1.w, SCALEW, f.y);
}

// epilogue LSE (contiguous mapping, plain weights)
__device__ __forceinline__ float lse_row(const __half* mat, const float4* wv,
                                         int row, int lane)
{
    const uint4* mr = (const uint4*)(mat + (size_t)row * P);
    const uint4 ca = mr[lane];
    const uint4 cb = mr[lane + 64];
    const float4 wa0 = wv[2 * lane],       wa1 = wv[2 * lane + 1];
    const float4 wb0 = wv[128 + 2 * lane], wb1 = wv[129 + 2 * lane];
    float zv[16];
    args8(ca, wa0, wa1, zv);
    args8(cb, wb0, wb1, zv + 8);
    float m = fmaxf(MAX4(zv[0], zv[1], zv[2], zv[3]), MAX4(zv[4], zv[5], zv[6], zv[7]));
    m = fmaxf(m, fmaxf(MAX4(zv[8], zv[9], zv[10], zv[11]), MAX4(zv[12], zv[13], zv[14], zv[15])));
#pragma unroll
    for (int off = 32; off; off >>= 1) m = fmaxf(m, __shfl_xor(m, off, 64));
    float s = 0.f;
#pragma unroll
    for (int q = 0; q < 16; q++) s += exp2f(zv[q] - m);
#pragma unroll
    for (int off = 32; off; off >>= 1) s += __shfl_xor(s, off, 64);
    return EPS_LOG_MU - EPSF_LN2 * (m + __log2f(s));
}

// ---------------- recompute v_T = F(u_T) ----------------
__global__ __launch_bounds__(256)
void colT_k(float* __restrict__ ws)
{
    const __half* zT = (const __half*)(ws + OFF_ZT);
    float* u = ws + OFF_U;
    float* v = ws + OFF_V;
    const int tid   = threadIdx.x;
    const int nB    = blockIdx.x & 7;
    const int inner = blockIdx.x >> 3;
    const int wid   = tid >> 6;
    const int lane  = tid & 63;
    const __half* zTb = zT + (size_t)nB * P * P;
    const float4* ur = (const float4*)(u + nB * P);
#pragma unroll
    for (int rr = 0; rr < 4; rr++) {
        const int col = inner * 16 + wid * 4 + rr;
        const float vn = lse_row(zTb, ur, col, lane);
        if (lane == 0) v[nB * P + col] = vn;
    }
}

// ---------------- final cost ----------------
__global__ __launch_bounds__(256)
void cost_k(float* __restrict__ ws)
{
    const __half* z = (const __half*)(ws + OFF_Z);
    float* u    = ws + OFF_U;
    float* v    = ws + OFF_V;
    float* cost = ws + OFF_COST;
    const int tid   = threadIdx.x;
    const int nB    = blockIdx.x & 7;
    const int inner = blockIdx.x >> 3;
    const int wid   = tid >> 6;
    const int lane  = tid & 63;
    __shared__ float red[4];

    const float4* vr = (const float4*)(v + nB * P);
    float accW = 0.f;
#pragma unroll
    for (int rr = 0; rr < 4; rr++) {
        const int row = inner * 16 + wid * 4 + rr;
        const uint4* mr = (const uint4*)(z + ((size_t)nB * P + row) * P);
        const uint4 ca = mr[lane];
        const uint4 cb = mr[lane + 64];
        const float4 va0 = vr[2 * lane],       va1 = vr[2 * lane + 1];
        const float4 vb0 = vr[128 + 2 * lane], vb1 = vr[129 + 2 * lane];
        float zw[16];
        args8(ca, va0, va1, zw);
        args8(cb, vb0, vb1, zw + 8);
        float zc[16];
        {
            const __half2* ha = (const __half2*)&ca;
            const __half2* hb = (const __half2*)&cb;
            float2 f;
            f = __half22float2(ha[0]); zc[0] = f.x;  zc[1] = f.y;
            f = __half22float2(ha[1]); zc[2] = f.x;  zc[3] = f.y;
            f = __half22float2(ha[2]); zc[4] = f.x;  zc[5] = f.y;
            f = __half22float2(ha[3]); zc[6] = f.x;  zc[7] = f.y;
            f = __half22float2(hb[0]); zc[8] = f.x;  zc[9] = f.y;
            f = __half22float2(hb[1]); zc[10] = f.x; zc[11] = f.y;
            f = __half22float2(hb[2]); zc[12] = f.x; zc[13] = f.y;
            f = __half22float2(hb[3]); zc[14] = f.x; zc[15] = f.y;
        }
        const float ui = u[nB * P + row] * SCALEW;
#pragma unroll
        for (int q = 0; q < 16; q++)
            accW += exp2f(zw[q] + ui) * zc[q];
    }
#pragma unroll
    for (int off = 32; off; off >>= 1) accW += __shfl_xor(accW, off, 64);
    if (lane == 0) red[wid] = accW;
    __syncthreads();
    if (tid == 0)
        atomicAdd(&cost[nB], -EPSF_LN2 * (red[0] + red[1] + red[2] + red[3]));
}

__global__ void out_k(const float* __restrict__ ws, float* __restrict__ out)
{
    if (threadIdx.x < NB) out[threadIdx.x] = ws[OFF_COST + threadIdx.x];
}

__global__ void sentinel_k(float* __restrict__ out)
{
    if (threadIdx.x < NB) out[threadIdx.x] = 1.0e6f;
}

extern "C" void kernel_launch(void* const* d_in, const int* in_sizes, int n_in,
                              void* d_out, int out_size, void* d_ws, size_t ws_size,
                              hipStream_t stream) {
    const float* x = (const float*)d_in[0];
    const float* y = (const float*)d_in[1];
    float* ws  = (float*)d_ws;
    float* out = (float*)d_out;

    if (ws_size < (size_t)WS_FLOATS * sizeof(float)) {
        sentinel_k<<<1, 64, 0, stream>>>(out);
        return;
    }

    init_k<<<32, 256, 0, stream>>>(x, y, ws);
    gemm_k<<<1024, 256, 0, stream>>>(x, y, ws);
    iter_k<<<IB, TPB_I, 0, stream>>>(ws);
    findT_k<<<1, 1024, 0, stream>>>(ws);
    colT_k<<<512, 256, 0, stream>>>(ws);
    cost_k<<<512, 256, 0, stream>>>(ws);
    out_k<<<1, 64, 0, stream>>>(ws, out);
}